// Round 12
// baseline (107.161 us; speedup 1.0000x reference)
//
#include <hip/hip_runtime.h>
#include <math.h>

#define NGRAPH 1000
#define NPG    100
#define EPG    1600
#define NF     32
#define NC     10
#define KP     30
#define OUTL   16
#define INL    97
#define NITER  3

#define NTV    512
#define NTF    1024

#define XSTR   36
#define FSTR   100
#define HSTR   36
#define PSTR   164
#define CSRMAX 1920
#define ZROW   (NPG * XSTR)

#define WS_EDGES_BYTES ((size_t)NGRAPH * EPG * 4)
#define WCAPB_UINT4    2560                       // 4 ksteps * 10 ntiles * 64 lanes
#define WS_V10_BYTES   (WS_EDGES_BYTES + (size_t)WCAPB_UINT4 * 16)

#define PIDX(i, c) ((i) * PSTR + (c) * OUTL)

typedef __attribute__((ext_vector_type(8))) short bf16x8;
typedef __attribute__((ext_vector_type(4))) float f32x4;

__device__ __forceinline__ float4 ld4(const float* p) { return *reinterpret_cast<const float4*>(p); }
__device__ __forceinline__ void st4(float* p, float4 v) { *reinterpret_cast<float4*>(p) = v; }
__device__ __forceinline__ float dot4(float4 a, float4 b) { return a.x*b.x + a.y*b.y + a.z*b.z + a.w*b.w; }
__device__ __forceinline__ float tanh_fast(float x) {
  float e = __expf(2.f * x);
  return 1.f - 2.f / (e + 1.f);
}
__device__ __forceinline__ unsigned f2bf(float f) {   // f32 -> bf16 (RNE)
  unsigned u = __float_as_uint(f);
  u += 0x7FFFu + ((u >> 16) & 1u);
  return u >> 16;
}

// ---- pre-kernel 1: transpose edges [k][g] -> [g][k], pack local (src<<8|dst)
__global__ void prek_edges(const int* __restrict__ esrc, const int* __restrict__ edst,
                           unsigned int* __restrict__ wsE) {
  __shared__ unsigned int t[64][65];
  const int kb = blockIdx.x % (EPG / 64);
  const int gb = blockIdx.x / (EPG / 64);
  const int lane = threadIdx.x & 63;
  const int row  = threadIdx.x >> 6;
  #pragma unroll
  for (int r = row; r < 64; r += 4) {
    int k = kb * 64 + r;
    int g = gb * 64 + lane;
    if (g < NGRAPH) {
      int idx = k * NGRAPH + g;
      int si = esrc[idx] - g * NPG;
      int di = edst[idx] - g * NPG;
      t[r][lane] = (unsigned int)((si << 8) | di);
    }
  }
  __syncthreads();
  #pragma unroll
  for (int r = row; r < 64; r += 4) {
    int g = gb * 64 + r;
    int k = kb * 64 + lane;
    if (g < NGRAPH) wsE[(size_t)g * EPG + k] = t[lane][r];
  }
}

// ---- pre-kernel 2: Wcap -> bf16 B-fragments for mfma_f32_16x16x32_bf16
__global__ void prek_capB(const float* __restrict__ Wcap, uint4* __restrict__ wcapB) {
  int o = blockIdx.x * 256 + threadIdx.x;
  if (o >= WCAPB_UINT4) return;
  int ks  = o / 640;
  int rem = o - ks * 640;
  int n   = rem >> 6;
  int ln  = rem & 63;
  int e   = ln & 15;
  int k0  = ks * 32 + ((ln >> 4) << 3);
  const float* wr = Wcap + (n * OUTL + e) * INL;
  unsigned v[8];
  #pragma unroll
  for (int j = 0; j < 8; ++j) {
    int k = k0 + j;
    v[j] = f2bf((k < INL) ? wr[k] : 0.f);
  }
  uint4 pk;
  pk.x = v[0] | (v[1] << 16); pk.y = v[2] | (v[3] << 16);
  pk.z = v[4] | (v[5] << 16); pk.w = v[6] | (v[7] << 16);
  wcapB[o] = pk;
}

// ======= v12: v11 with A6a coverage fix (grid-stride, 800 items on 512 threads) =======
struct SMemV11 {
  float feat[NPG * FSTR];                // 40000
  union {
    struct {                             // phase A
      float hs[(NPG + 1) * XSTR];        // 14544 (row 100 = zeros)
      float W[NF * NF];                  // 4096
      float W4s[NF];                     // 128
      float bias2[2][NF];                // 256
      float b4s;                         // 4
      unsigned short csr16[CSRMAX];      // 3840
      int cnt[NPG];                      // 400
      float dinv[NPG];                   // 400
      int ptr[NPG + 1];                  // 404
    } a;
    struct {                             // phase B
      uint4 pooledB[512];                // 8192 : bf16 A-fragments
    } b;
  } u;
  int order[KP];
};                                       // ~64.2 KB -> 2 blocks/CU

__global__ __launch_bounds__(NTV, 4) void gcn_caps_v12(
    const float* __restrict__ x,
    const unsigned int* __restrict__ wsE,
    const float* __restrict__ W1, const float* __restrict__ b1,
    const float* __restrict__ W2, const float* __restrict__ b2,
    const float* __restrict__ W3, const float* __restrict__ b3,
    const float* __restrict__ W4, const float* __restrict__ b4,
    const uint4* __restrict__ wcapB,
    float* __restrict__ out)
{
  extern __shared__ char smraw[];
  SMemV11& s = *reinterpret_cast<SMemV11*>(smraw);
  const int g = blockIdx.x;
  const int tid = threadIdx.x;

  // A1: zero counters + hs pad-row, stage W1/b1
  if (tid < NPG) s.u.a.cnt[tid] = 0;
  if (tid >= 128 && tid < 128 + XSTR) s.u.a.hs[ZROW + (tid - 128)] = 0.f;
  for (int i = tid; i < NF * NF; i += NTV) s.u.a.W[i] = W1[i];
  if (tid < NF) s.u.a.bias2[0][tid] = b1[tid];
  __syncthreads();

  // A2: degree count
  const unsigned int* eg = wsE + (size_t)g * EPG;
  for (int k = tid; k < EPG; k += NTV) atomicAdd(&s.u.a.cnt[eg[k] & 0xFF], 1);
  __syncthreads();

  // A3 (merged): scan over padded counts + dinv + cursors + pad-fill, single wave
  if (tid < 64) {
    int j = tid;
    int n0 = 2 * j, n1 = 2 * j + 1;
    int r0 = (n0 < NPG) ? s.u.a.cnt[n0] : 0;
    int r1 = (n1 < NPG) ? s.u.a.cnt[n1] : 0;
    int q0 = (r0 + 3) & ~3, q1 = (r1 + 3) & ~3;
    int t = q0 + q1;
    int run = t;
    #pragma unroll
    for (int off = 1; off < 64; off <<= 1) {
      int u = __shfl_up(run, off);
      if (j >= off) run += u;
    }
    int excl = run - t;
    if (n0 < NPG) {
      s.u.a.ptr[n0] = excl;
      s.u.a.dinv[n0] = rsqrtf((float)r0 + 1.0f);
      s.u.a.cnt[n0] = excl;
      for (int k = excl + r0; k < excl + q0; ++k) s.u.a.csr16[k] = (unsigned short)ZROW;
    }
    if (n1 < NPG) {
      int e1 = excl + q0;
      s.u.a.ptr[n1] = e1;
      s.u.a.dinv[n1] = rsqrtf((float)r1 + 1.0f);
      s.u.a.cnt[n1] = e1;
      for (int k = e1 + r1; k < e1 + q1; ++k) s.u.a.csr16[k] = (unsigned short)ZROW;
    }
    if (j == 63) s.u.a.ptr[NPG] = run;
  }
  __syncthreads();

  // A4: CSR fill (offsets pre-multiplied by XSTR)
  for (int k = tid; k < EPG; k += NTV) {
    unsigned int p = eg[k];
    int pos = atomicAdd(&s.u.a.cnt[p & 0xFF], 1);
    s.u.a.csr16[pos] = (unsigned short)(((p >> 8) & 0xFF) * XSTR);
  }
  __syncthreads();

  const float4* xr = reinterpret_cast<const float4*>(x + (size_t)g * NPG * NF);

  // A5: three 32-wide GCN layers
  for (int l = 0; l < 3; ++l) {
    // GEMM, 4-node register-blocked on 200 threads
    if (tid < 25 * 8) {
      int nd = tid >> 3, cq = tid & 7;
      float4 ac0 = make_float4(0,0,0,0), ac1 = ac0, ac2 = ac0, ac3 = ac0;
      #pragma unroll
      for (int kq = 0; kq < 8; ++kq) {
        float4 a0, a1, a2, a3;
        if (l == 0) {
          a0 = xr[(nd     ) * 8 + kq]; a1 = xr[(nd + 25) * 8 + kq];
          a2 = xr[(nd + 50) * 8 + kq]; a3 = xr[(nd + 75) * 8 + kq];
        } else {
          int cb = (l - 1) * NF + kq * 4;
          a0 = ld4(&s.feat[(nd     ) * FSTR + cb]);
          a1 = ld4(&s.feat[(nd + 25) * FSTR + cb]);
          a2 = ld4(&s.feat[(nd + 50) * FSTR + cb]);
          a3 = ld4(&s.feat[(nd + 75) * FSTR + cb]);
        }
        const float v0[4] = {a0.x, a0.y, a0.z, a0.w};
        const float v1[4] = {a1.x, a1.y, a1.z, a1.w};
        const float v2[4] = {a2.x, a2.y, a2.z, a2.w};
        const float v3[4] = {a3.x, a3.y, a3.z, a3.w};
        #pragma unroll
        for (int j = 0; j < 4; ++j) {
          float4 w4 = ld4(&s.u.a.W[(kq * 4 + j) * NF + cq * 4]);
          ac0.x += v0[j]*w4.x; ac0.y += v0[j]*w4.y; ac0.z += v0[j]*w4.z; ac0.w += v0[j]*w4.w;
          ac1.x += v1[j]*w4.x; ac1.y += v1[j]*w4.y; ac1.z += v1[j]*w4.z; ac1.w += v1[j]*w4.w;
          ac2.x += v2[j]*w4.x; ac2.y += v2[j]*w4.y; ac2.z += v2[j]*w4.z; ac2.w += v2[j]*w4.w;
          ac3.x += v3[j]*w4.x; ac3.y += v3[j]*w4.y; ac3.z += v3[j]*w4.z; ac3.w += v3[j]*w4.w;
        }
      }
      float d0 = s.u.a.dinv[nd], d1 = s.u.a.dinv[nd + 25];
      float d2 = s.u.a.dinv[nd + 50], d3 = s.u.a.dinv[nd + 75];
      ac0.x*=d0; ac0.y*=d0; ac0.z*=d0; ac0.w*=d0;
      ac1.x*=d1; ac1.y*=d1; ac1.z*=d1; ac1.w*=d1;
      ac2.x*=d2; ac2.y*=d2; ac2.z*=d2; ac2.w*=d2;
      ac3.x*=d3; ac3.y*=d3; ac3.z*=d3; ac3.w*=d3;
      st4(&s.u.a.hs[(nd     ) * XSTR + cq * 4], ac0);
      st4(&s.u.a.hs[(nd + 25) * XSTR + cq * 4], ac1);
      st4(&s.u.a.hs[(nd + 50) * XSTR + cq * 4], ac2);
      st4(&s.u.a.hs[(nd + 75) * XSTR + cq * 4], ac3);
    }
    __syncthreads();

    // prefetch next weights (AGG never reads W/W4s/b4s)
    if (l == 0) {
      for (int i = tid; i < NF * NF; i += NTV) s.u.a.W[i] = W2[i];
      if (tid < NF) s.u.a.bias2[1][tid] = b2[tid];
    } else if (l == 1) {
      for (int i = tid; i < NF * NF; i += NTV) s.u.a.W[i] = W3[i];
      if (tid < NF) s.u.a.bias2[0][tid] = b3[tid];
      if (tid >= 64 && tid < 64 + NF) s.u.a.W4s[tid - 64] = W4[tid - 64];
      if (tid == NTV - 1) s.u.a.b4s = b4[0];
    }

    // AGG split-gather: item = (d, fq, half); shfl-combine lane^8
    for (int o = tid; o < NPG * 16; o += NTV) {
      int d = o >> 4, fq4 = (o & 7) * 4, h = (o >> 3) & 1;
      int p0 = s.u.a.ptr[d], p1 = s.u.a.ptr[d + 1];
      float4 r = (h == 0) ? ld4(&s.u.a.hs[d * XSTR + fq4])
                          : make_float4(0.f, 0.f, 0.f, 0.f);
      for (int idx = p0 + h * 4; idx < p1; idx += 8) {
        uint2 c2 = *reinterpret_cast<const uint2*>(&s.u.a.csr16[idx]);
        int o0 = c2.x & 0xFFFF, o1 = c2.x >> 16;
        int o2 = c2.y & 0xFFFF, o3 = c2.y >> 16;
        float4 h0 = ld4(&s.u.a.hs[o0 + fq4]);
        float4 h1 = ld4(&s.u.a.hs[o1 + fq4]);
        float4 h2 = ld4(&s.u.a.hs[o2 + fq4]);
        float4 h3 = ld4(&s.u.a.hs[o3 + fq4]);
        r.x += (h0.x + h1.x) + (h2.x + h3.x);
        r.y += (h0.y + h1.y) + (h2.y + h3.y);
        r.z += (h0.z + h1.z) + (h2.z + h3.z);
        r.w += (h0.w + h1.w) + (h2.w + h3.w);
      }
      r.x += __shfl_xor(r.x, 8);
      r.y += __shfl_xor(r.y, 8);
      r.z += __shfl_xor(r.z, 8);
      r.w += __shfl_xor(r.w, 8);
      if (h == 0) {
        const float* bc = s.u.a.bias2[l & 1];
        float4 bq = ld4(&bc[fq4]);
        float di = s.u.a.dinv[d];
        float4 oo;
        oo.x = tanh_fast(di * r.x + bq.x);
        oo.y = tanh_fast(di * r.y + bq.y);
        oo.z = tanh_fast(di * r.z + bq.z);
        oo.w = tanh_fast(di * r.w + bq.w);
        st4(&s.feat[d * FSTR + l * NF + fq4], oo);
      }
    }
    __syncthreads();
  }

  // A6a: layer-4 GEMM, 8 lanes/node, GRID-STRIDE over 800 items (v11 bug: if(tid<800) on 512 threads)
  for (int o = tid; o < NPG * 8; o += NTV) {
    int d = o >> 3, fq4 = (o & 7) * 4;
    float r = dot4(ld4(&s.feat[d * FSTR + 2 * NF + fq4]), ld4(&s.u.a.W4s[fq4]));
    r += __shfl_xor(r, 1);
    r += __shfl_xor(r, 2);
    r += __shfl_xor(r, 4);
    if ((o & 7) == 0) s.u.a.hs[d * XSTR] = r * s.u.a.dinv[d];
  }
  __syncthreads();

  // A6b: layer-4 aggregation: 8 lanes per node, stride-8 walk + shfl reduce
  for (int o = tid; o < NPG * 8; o += NTV) {
    int d = o >> 3, p = o & 7;
    int p0 = s.u.a.ptr[d], p1 = s.u.a.ptr[d + 1];
    float r = (p == 0) ? s.u.a.hs[d * XSTR] : 0.f;
    for (int idx = p0 + p; idx < p1; idx += 8) r += s.u.a.hs[s.u.a.csr16[idx]];
    r += __shfl_xor(r, 1);
    r += __shfl_xor(r, 2);
    r += __shfl_xor(r, 4);
    if (p == 0)
      s.feat[d * FSTR + 96] = tanh_fast(s.u.a.dinv[d] * r + s.u.a.b4s);
  }
  __syncthreads();

  // A7: stable top-30 by col96 desc (exact f32)
  if (tid < NPG * 4) {
    int i = tid >> 2, p = tid & 3;
    float vv = s.feat[i * FSTR + 96];
    int j0 = p * 25, j1 = j0 + 25;
    int rank = 0;
    for (int j = j0; j < j1; ++j) {
      float vj = s.feat[j * FSTR + 96];
      rank += (vj > vv) || (vj == vv && j < i);
    }
    rank += __shfl_xor(rank, 1);
    rank += __shfl_xor(rank, 2);
    if (p == 0 && rank < KP) s.order[rank] = i;
  }
  __syncthreads();   // phase-A union dead after this

  // B1: pack pooled rows into bf16 A-fragments (one 16B frag per thread)
  {
    int mt = tid >> 8, ks = (tid >> 6) & 3, ln = tid & 63;
    int i = mt * 16 + (ln & 15);
    int k0 = ks * 32 + ((ln >> 4) << 3);
    uint4 pk = make_uint4(0, 0, 0, 0);
    if (i < KP) {
      int row = s.order[i] * FSTR;
      float f[8];
      if (ks < 3) {
        float4 x0 = ld4(&s.feat[row + k0]);
        float4 x1 = ld4(&s.feat[row + k0 + 4]);
        f[0]=x0.x; f[1]=x0.y; f[2]=x0.z; f[3]=x0.w;
        f[4]=x1.x; f[5]=x1.y; f[6]=x1.z; f[7]=x1.w;
      } else {
        #pragma unroll
        for (int j = 0; j < 8; ++j) f[j] = 0.f;
        if (k0 == 96) f[0] = s.feat[row + 96];
      }
      pk.x = f2bf(f[0]) | (f2bf(f[1]) << 16);
      pk.y = f2bf(f[2]) | (f2bf(f[3]) << 16);
      pk.z = f2bf(f[4]) | (f2bf(f[5]) << 16);
      pk.w = f2bf(f[6]) | (f2bf(f[7]) << 16);
    }
    s.u.b.pooledB[(mt * 4 + ks) * 64 + ln] = pk;
  }
  __syncthreads();

  // B2R: MFMA priors + in-register routing (barrier-free after this point)
  if (tid < 5 * 64) {
    int w = tid >> 6, ln = tid & 63;
    int q = ln >> 4;
    bf16x8 afr[2][4];
    #pragma unroll
    for (int mt = 0; mt < 2; ++mt)
      #pragma unroll
      for (int ks = 0; ks < 4; ++ks)
        afr[mt][ks] = __builtin_bit_cast(bf16x8, s.u.b.pooledB[(mt * 4 + ks) * 64 + ln]);
    #pragma unroll
    for (int nn = 0; nn < 2; ++nn) {
      int n = w * 2 + nn;
      f32x4 acc0 = {0.f, 0.f, 0.f, 0.f}, acc1 = {0.f, 0.f, 0.f, 0.f};
      #pragma unroll
      for (int ks = 0; ks < 4; ++ks) {
        bf16x8 bfr = __builtin_bit_cast(bf16x8, wcapB[(ks * 10 + n) * 64 + ln]);
        acc0 = __builtin_amdgcn_mfma_f32_16x16x32_bf16(afr[0][ks], bfr, acc0, 0, 0, 0);
        acc1 = __builtin_amdgcn_mfma_f32_16x16x32_bf16(afr[1][ks], bfr, acc1, 0, 0, 0);
      }
      // slot sl = mt*4 + j  -> i = mt*16 + q*4 + j ; e = ln & 15
      float p[8];
      #pragma unroll
      for (int j = 0; j < 4; ++j) { p[j] = acc0[j]; p[4 + j] = acc1[j]; }
      float prsq[8];
      #pragma unroll
      for (int sl = 0; sl < 8; ++sl) {           // reduce over e: xor 1,2,4,8
        float t = p[sl] * p[sl];
        t += __shfl_xor(t, 1); t += __shfl_xor(t, 2);
        t += __shfl_xor(t, 4); t += __shfl_xor(t, 8);
        prsq[sl] = t;
      }
      float outv = 0.f;                           // out init: mean over i
      #pragma unroll
      for (int sl = 0; sl < 8; ++sl) outv += p[sl];   // invalid rows are zero
      outv += __shfl_xor(outv, 16); outv += __shfl_xor(outv, 32);
      outv *= (1.0f / KP);
      #pragma unroll
      for (int it = 0; it < NITER; ++it) {
        float oq = outv * outv;
        oq += __shfl_xor(oq, 1); oq += __shfl_xor(oq, 2);
        oq += __shfl_xor(oq, 4); oq += __shfl_xor(oq, 8);
        float sim[8];
        #pragma unroll
        for (int sl = 0; sl < 8; ++sl) {
          float t = p[sl] * outv;
          t += __shfl_xor(t, 1); t += __shfl_xor(t, 2);
          t += __shfl_xor(t, 4); t += __shfl_xor(t, 8);
          sim[sl] = t / (prsq[sl] + oq - t);
        }
        float m = -1e30f;
        #pragma unroll
        for (int sl = 0; sl < 8; ++sl) {
          int i = ((sl >> 2) << 4) + (q << 2) + (sl & 3);
          if (i < KP) m = fmaxf(m, sim[sl]);
        }
        m = fmaxf(m, __shfl_xor(m, 16)); m = fmaxf(m, __shfl_xor(m, 32));
        float ssum = 0.f, onew = 0.f;
        #pragma unroll
        for (int sl = 0; sl < 8; ++sl) {
          int i = ((sl >> 2) << 4) + (q << 2) + (sl & 3);
          float wg = (i < KP) ? __expf(sim[sl] - m) : 0.f;
          ssum += wg;
          onew += wg * p[sl];
        }
        ssum += __shfl_xor(ssum, 16); ssum += __shfl_xor(ssum, 32);
        onew += __shfl_xor(onew, 16); onew += __shfl_xor(onew, 32);
        outv = onew / ssum;
      }
      float t = outv * outv;                      // ||out|| over e
      t += __shfl_xor(t, 1); t += __shfl_xor(t, 2);
      t += __shfl_xor(t, 4); t += __shfl_xor(t, 8);
      if (ln == 0) out[(size_t)g * NC + n] = sqrtf(t);
    }
  }
}

// ==================== fused fallback (proven R4 kernel, no ws needed) ====================
struct SMemF {
  float feat[NPG * FSTR];
  union {
    unsigned short epack[EPG];
    float priors[KP * PSTR];
  } u;
  union {
    float hs[NPG * HSTR];
    struct {
      float prsq[KP * NC];
      float simbuf[KP * NC];
      float outv[NC * OUTL];
      float smax[NC];
      float ssum[NC];
      int   order[KP];
    } r;
  } v;
  float W[NF * NF];
  float bias2[2][NF];
  unsigned char csr[EPG];
  int ptr[NPG + 1];
  int cnt[NPG];
  float dinv[NPG];
};

__global__ __launch_bounds__(NTF, 8) void gcn_caps_fused(
    const float* __restrict__ x,
    const int* __restrict__ esrc, const int* __restrict__ edst,
    const float* __restrict__ W1, const float* __restrict__ b1,
    const float* __restrict__ W2, const float* __restrict__ b2,
    const float* __restrict__ W3, const float* __restrict__ b3,
    const float* __restrict__ W4, const float* __restrict__ b4,
    const float* __restrict__ Wcap,
    float* __restrict__ out)
{
  extern __shared__ char smem_raw[];
  SMemF& s = *reinterpret_cast<SMemF*>(smem_raw);
  const int g = blockIdx.x;
  const int tid = threadIdx.x;

  if (tid < NPG) s.cnt[tid] = 0;
  for (int i = tid; i < NF * NF; i += NTF) s.W[i] = W1[i];
  if (tid < NF) s.bias2[0][tid] = b1[tid];
  __syncthreads();

  for (int k = tid; k < EPG; k += NTF) {
    int si = esrc[g + k * NGRAPH] - g * NPG;
    int di = edst[g + k * NGRAPH] - g * NPG;
    s.u.epack[k] = (unsigned short)((si << 8) | di);
    atomicAdd(&s.cnt[di], 1);
  }
  __syncthreads();

  if (tid < 64) {
    int j = tid;
    int a0 = (2 * j < NPG) ? s.cnt[2 * j] : 0;
    int a1 = (2 * j + 1 < NPG) ? s.cnt[2 * j + 1] : 0;
    int t = a0 + a1;
    int run = t;
    #pragma unroll
    for (int off = 1; off < 64; off <<= 1) {
      int u = __shfl_up(run, off);
      if (j >= off) run += u;
    }
    int excl = run - t;
    if (2 * j < NPG) s.ptr[2 * j] = excl;
    if (2 * j + 1 < NPG) s.ptr[2 * j + 1] = excl + a0;
    if (j == 63) s.ptr[NPG] = run;
  }
  __syncthreads();
  if (tid < NPG) {
    s.dinv[tid] = rsqrtf((float)s.cnt[tid] + 1.0f);
    s.cnt[tid] = s.ptr[tid];
  }
  __syncthreads();

  for (int k = tid; k < EPG; k += NTF) {
    int pk = s.u.epack[k];
    int pos = atomicAdd(&s.cnt[pk & 0xFF], 1);
    s.csr[pos] = (unsigned char)(pk >> 8);
  }
  __syncthreads();

  const float4* xr = reinterpret_cast<const float4*>(x + (size_t)g * NPG * NF);
  for (int l = 0; l < 3; ++l) {
    if (tid < NPG * 8) {
      int node = tid >> 3, cq = tid & 7;
      float4 acc = make_float4(0.f, 0.f, 0.f, 0.f);
      #pragma unroll
      for (int kq = 0; kq < 8; ++kq) {
        float4 a4 = (l == 0) ? xr[node * 8 + kq]
                             : ld4(&s.feat[node * FSTR + (l - 1) * NF + kq * 4]);
        const float av[4] = {a4.x, a4.y, a4.z, a4.w};
        #pragma unroll
        for (int j = 0; j < 4; ++j) {
          float4 w4 = ld4(&s.W[(kq * 4 + j) * NF + cq * 4]);
          acc.x += av[j] * w4.x; acc.y += av[j] * w4.y;
          acc.z += av[j] * w4.z; acc.w += av[j] * w4.w;
        }
      }
      float di = s.dinv[node];
      acc.x *= di; acc.y *= di; acc.z *= di; acc.w *= di;
      st4(&s.v.hs[node * HSTR + ((cq ^ (node >> 3)) & 7) * 4], acc);
    }
    __syncthreads();

    if (l == 0) {
      for (int i = tid; i < NF * NF; i += NTF) s.W[i] = W2[i];
      if (tid < NF) s.bias2[1][tid] = b2[tid];
    } else if (l == 1) {
      for (int i = tid; i < NF * NF; i += NTF) s.W[i] = W3[i];
      if (tid < NF) s.bias2[0][tid] = b3[tid];
    } else {
      if (tid < NF) s.W[tid] = W4[tid];
      if (tid == NTF - 1) s.bias2[1][0] = b4[0];
    }

    if (tid < NPG * 8) {
      int d = tid >> 3, fq = tid & 7;
      const float* bc = s.bias2[l & 1];
      float4 b4q = ld4(&bc[fq * 4]);
      float4 r = ld4(&s.v.hs[d * HSTR + ((fq ^ (d >> 3)) & 7) * 4]);
      int p0 = s.ptr[d], p1 = s.ptr[d + 1];
      int idx = p0;
      for (; idx + 1 < p1; idx += 2) {
        int sc0 = s.csr[idx], sc1 = s.csr[idx + 1];
        float4 h0 = ld4(&s.v.hs[sc0 * HSTR + ((fq ^ (sc0 >> 3)) & 7) * 4]);
        float4 h1 = ld4(&s.v.hs[sc1 * HSTR + ((fq ^ (sc1 >> 3)) & 7) * 4]);
        r.x += h0.x + h1.x; r.y += h0.y + h1.y;
        r.z += h0.z + h1.z; r.w += h0.w + h1.w;
      }
      if (idx < p1) {
        int sc = s.csr[idx];
        float4 hq = ld4(&s.v.hs[sc * HSTR + ((fq ^ (sc >> 3)) & 7) * 4]);
        r.x += hq.x; r.y += hq.y; r.z += hq.z; r.w += hq.w;
      }
      float di = s.dinv[d];
      float4 o;
      o.x = tanh_fast(di * r.x + b4q.x);
      o.y = tanh_fast(di * r.y + b4q.y);
      o.z = tanh_fast(di * r.z + b4q.z);
      o.w = tanh_fast(di * r.w + b4q.w);
      st4(&s.feat[d * FSTR + l * NF + fq * 4], o);
    }
    __syncthreads();
  }

  float* hsf = s.v.hs;
  if (tid < NPG) {
    float a = 0.f;
    #pragma unroll
    for (int kq = 0; kq < 8; ++kq)
      a += dot4(ld4(&s.feat[tid * FSTR + 64 + kq * 4]), ld4(&s.W[kq * 4]));
    hsf[tid] = a * s.dinv[tid];
  }
  __syncthreads();
  if (tid < NPG) {
    float r = hsf[tid];
    int p0 = s.ptr[tid], p1 = s.ptr[tid + 1];
    for (int idx = p0; idx < p1; ++idx) r += hsf[s.csr[idx]];
    s.feat[tid * FSTR + 96] = tanh_fast(s.dinv[tid] * r + s.bias2[1][0]);
  }
  __syncthreads();

  if (tid < NPG * 8) {
    int i = tid >> 3, p = tid & 7;
    float vv = s.feat[i * FSTR + 96];
    int j0 = p * 13, j1 = min(NPG, j0 + 13);
    int rank = 0;
    for (int j = j0; j < j1; ++j) {
      float vj = s.feat[j * FSTR + 96];
      rank += (vj > vv) || (vj == vv && j < i);
    }
    rank += __shfl_xor(rank, 1);
    rank += __shfl_xor(rank, 2);
    rank += __shfl_xor(rank, 4);
    if (p == 0 && rank < KP) s.v.r.order[rank] = i;
  }
  __syncthreads();

  if (tid < KP * OUTL) {
    int i = tid >> 4, e = tid & 15;
    int row = s.v.r.order[i] * FSTR;
    float acc[NC];
    #pragma unroll
    for (int c = 0; c < NC; ++c) acc[c] = 0.f;
    for (int c = 0; c < NC; ++c) {
      float a = 0.f;
      for (int l = 0; l < INL; ++l) a += s.feat[row + l] * Wcap[(c * OUTL + e) * INL + l];
      acc[c] = a;
    }
    #pragma unroll
    for (int c = 0; c < NC; ++c) s.u.priors[PIDX(i, c) + e] = acc[c];
  }
  __syncthreads();

  if (tid < KP * NC) {
    int i = tid / NC, c = tid % NC;
    const float* pr = &s.u.priors[PIDX(i, c)];
    float a = 0.f;
    #pragma unroll
    for (int eq = 0; eq < 4; ++eq) { float4 p = ld4(pr + eq * 4); a += dot4(p, p); }
    s.v.r.prsq[tid] = a;
  }
  if (tid < NC * OUTL) {
    int c = tid >> 4, e = tid & 15;
    float a = 0.f;
    #pragma unroll
    for (int i = 0; i < KP; ++i) a += s.u.priors[PIDX(i, c) + e];
    s.v.r.outv[tid] = a * (1.0f / KP);
  }
  __syncthreads();

  for (int it = 0; it < NITER; ++it) {
    if (tid < KP * NC) {
      int i = tid / NC, c = tid % NC;
      const float* pr = &s.u.priors[PIDX(i, c)];
      const float* ov = &s.v.r.outv[c * OUTL];
      float xy = 0.f, oq = 0.f;
      #pragma unroll
      for (int eq = 0; eq < 4; ++eq) {
        float4 p = ld4(pr + eq * 4);
        float4 o = ld4(ov + eq * 4);
        xy += dot4(p, o); oq += dot4(o, o);
      }
      s.v.r.simbuf[tid] = xy / (s.v.r.prsq[tid] + oq - xy);
    }
    __syncthreads();
    if (tid < NC) {
      float m = -1e30f;
      #pragma unroll
      for (int i = 0; i < KP; ++i) m = fmaxf(m, s.v.r.simbuf[i * NC + tid]);
      float ss = 0.f;
      #pragma unroll
      for (int i = 0; i < KP; ++i) ss += __expf(s.v.r.simbuf[i * NC + tid] - m);
      s.v.r.smax[tid] = m;
      s.v.r.ssum[tid] = 1.f / ss;
    }
    __syncthreads();
    if (tid < NC * OUTL) {
      int c = tid >> 4, e = tid & 15;
      float m = s.v.r.smax[c], is = s.v.r.ssum[c], a = 0.f;
      #pragma unroll
      for (int i = 0; i < KP; ++i)
        a += __expf(s.v.r.simbuf[i * NC + c] - m) * s.u.priors[PIDX(i, c) + e];
      s.v.r.outv[tid] = a * is;
    }
    __syncthreads();
  }

  if (tid < NC) {
    const float* ov = &s.v.r.outv[tid * OUTL];
    float a = 0.f;
    #pragma unroll
    for (int eq = 0; eq < 4; ++eq) { float4 o = ld4(ov + eq * 4); a += dot4(o, o); }
    out[(size_t)g * NC + tid] = sqrtf(a);
  }
}

extern "C" void kernel_launch(void* const* d_in, const int* in_sizes, int n_in,
                              void* d_out, int out_size, void* d_ws, size_t ws_size,
                              hipStream_t stream) {
  const float* x    = (const float*)d_in[0];
  const int*   esrc = (const int*)d_in[1];
  const int*   edst = (const int*)d_in[2];
  const float* W1 = (const float*)d_in[4];
  const float* b1 = (const float*)d_in[5];
  const float* W2 = (const float*)d_in[6];
  const float* b2 = (const float*)d_in[7];
  const float* W3 = (const float*)d_in[8];
  const float* b3 = (const float*)d_in[9];
  const float* W4 = (const float*)d_in[10];
  const float* b4 = (const float*)d_in[11];
  const float* Wcap = (const float*)d_in[12];
  float* outp = (float*)d_out;

  if (ws_size >= WS_V10_BYTES) {
    unsigned int* wsE = (unsigned int*)d_ws;
    uint4* wcapB = (uint4*)((char*)d_ws + WS_EDGES_BYTES);
    (void)hipFuncSetAttribute((const void*)gcn_caps_v12,
                              hipFuncAttributeMaxDynamicSharedMemorySize, (int)sizeof(SMemV11));
    prek_edges<<<(EPG / 64) * 16, 256, 0, stream>>>(esrc, edst, wsE);
    prek_capB<<<(WCAPB_UINT4 + 255) / 256, 256, 0, stream>>>(Wcap, wcapB);
    gcn_caps_v12<<<NGRAPH, NTV, sizeof(SMemV11), stream>>>(
        x, wsE, W1, b1, W2, b2, W3, b3, W4, b4, wcapB, outp);
  } else {
    (void)hipFuncSetAttribute((const void*)gcn_caps_fused,
                              hipFuncAttributeMaxDynamicSharedMemorySize, (int)sizeof(SMemF));
    gcn_caps_fused<<<NGRAPH, NTF, sizeof(SMemF), stream>>>(
        x, esrc, edst, W1, b1, W2, b2, W3, b3, W4, b4, Wcap, outp);
  }
}

// Round 13
// 81.368 us; speedup vs baseline: 1.3170x; 1.3170x over previous
//
#include <hip/hip_runtime.h>
#include <math.h>

#define NGRAPH 1000
#define NPG    100
#define EPG    1600
#define NF     32
#define NC     10
#define KP     30
#define OUTL   16
#define INL    97
#define NITER  3

#define NTV    512
#define NTF    1024

#define XSTR   36
#define FSTR   100
#define HSTR   36
#define PSTR   164
#define CSRMAX 1920
#define ZROW   (NPG * XSTR)

#define WS_EDGES_BYTES ((size_t)NGRAPH * EPG * 4)
#define WCAPB_UINT4    2560                       // 4 ksteps * 10 ntiles * 64 lanes
#define WS_V10_BYTES   (WS_EDGES_BYTES + (size_t)WCAPB_UINT4 * 16)

#define PIDX(i, c) ((i) * PSTR + (c) * OUTL)

typedef __attribute__((ext_vector_type(8))) short bf16x8;
typedef __attribute__((ext_vector_type(4))) float f32x4;

__device__ __forceinline__ float4 ld4(const float* p) { return *reinterpret_cast<const float4*>(p); }
__device__ __forceinline__ void st4(float* p, float4 v) { *reinterpret_cast<float4*>(p) = v; }
__device__ __forceinline__ float dot4(float4 a, float4 b) { return a.x*b.x + a.y*b.y + a.z*b.z + a.w*b.w; }
__device__ __forceinline__ float tanh_fast(float x) {
  float e = __expf(2.f * x);
  return 1.f - 2.f / (e + 1.f);
}
__device__ __forceinline__ unsigned f2bf(float f) {   // f32 -> bf16 (RNE)
  unsigned u = __float_as_uint(f);
  u += 0x7FFFu + ((u >> 16) & 1u);
  return u >> 16;
}

// ---- pre-kernel 1: transpose edges [k][g] -> [g][k], pack local (src<<8|dst)
__global__ void prek_edges(const int* __restrict__ esrc, const int* __restrict__ edst,
                           unsigned int* __restrict__ wsE) {
  __shared__ unsigned int t[64][65];
  const int kb = blockIdx.x % (EPG / 64);
  const int gb = blockIdx.x / (EPG / 64);
  const int lane = threadIdx.x & 63;
  const int row  = threadIdx.x >> 6;
  #pragma unroll
  for (int r = row; r < 64; r += 4) {
    int k = kb * 64 + r;
    int g = gb * 64 + lane;
    if (g < NGRAPH) {
      int idx = k * NGRAPH + g;
      int si = esrc[idx] - g * NPG;
      int di = edst[idx] - g * NPG;
      t[r][lane] = (unsigned int)((si << 8) | di);
    }
  }
  __syncthreads();
  #pragma unroll
  for (int r = row; r < 64; r += 4) {
    int g = gb * 64 + r;
    int k = kb * 64 + lane;
    if (g < NGRAPH) wsE[(size_t)g * EPG + k] = t[lane][r];
  }
}

// ---- pre-kernel 2: Wcap -> bf16 B-fragments for mfma_f32_16x16x32_bf16
// B[k][col] with col = c*16+e; frag entry (kstep, ntile=c, lane): k = kstep*32+(lane>>4)*8+j
__global__ void prek_capB(const float* __restrict__ Wcap, uint4* __restrict__ wcapB) {
  int o = blockIdx.x * 256 + threadIdx.x;
  if (o >= WCAPB_UINT4) return;
  int ks  = o / 640;
  int rem = o - ks * 640;
  int n   = rem >> 6;
  int ln  = rem & 63;
  int e   = ln & 15;
  int k0  = ks * 32 + ((ln >> 4) << 3);
  const float* wr = Wcap + (n * OUTL + e) * INL;
  unsigned v[8];
  #pragma unroll
  for (int j = 0; j < 8; ++j) {
    int k = k0 + j;
    v[j] = f2bf((k < INL) ? wr[k] : 0.f);
  }
  uint4 pk;
  pk.x = v[0] | (v[1] << 16); pk.y = v[2] | (v[3] << 16);
  pk.z = v[4] | (v[5] << 16); pk.w = v[6] | (v[7] << 16);
  wcapB[o] = pk;
}

// ======= v13: v10 (proven 82us) + merged A3 scan phase (proven in v12) =======
struct SMemV13 {
  float feat[NPG * FSTR];                // 40000
  union {
    struct {                             // phase A
      float hs[(NPG + 1) * XSTR];        // 14544 (row 100 = zeros)
      float W[NF * NF];                  // 4096
      float bias2[2][NF];                // 256
      unsigned short csr16[CSRMAX];      // 3840
      int cnt[NPG];                      // 400
      float dinv[NPG];                   // 400
      int ptr[NPG + 1];                  // 404
    } a;
    struct {                             // phase B
      float priors[KP * PSTR];           // 19680
      float prsq[KP * NC];               // 1200
      float simbuf[KP * NC];             // 1200
      float outv[NC * OUTL];             // 640
      uint4 pooledB[512];                // 8192 : bf16 A-fragments
    } b;
  } u;
  int order[KP];
};                                       // ~71 KB -> 2 blocks/CU (dynamic LDS)

__global__ __launch_bounds__(NTV, 4) void gcn_caps_v13(
    const float* __restrict__ x,
    const unsigned int* __restrict__ wsE,
    const float* __restrict__ W1, const float* __restrict__ b1,
    const float* __restrict__ W2, const float* __restrict__ b2,
    const float* __restrict__ W3, const float* __restrict__ b3,
    const float* __restrict__ W4, const float* __restrict__ b4,
    const uint4* __restrict__ wcapB,
    float* __restrict__ out)
{
  extern __shared__ char smraw[];
  SMemV13& s = *reinterpret_cast<SMemV13*>(smraw);
  const int g = blockIdx.x;
  const int tid = threadIdx.x;

  // A1: zero counters + hs pad-row, stage W1/b1
  if (tid < NPG) s.u.a.cnt[tid] = 0;
  if (tid >= 128 && tid < 128 + XSTR) s.u.a.hs[ZROW + (tid - 128)] = 0.f;
  for (int i = tid; i < NF * NF; i += NTV) s.u.a.W[i] = W1[i];
  if (tid < NF) s.u.a.bias2[0][tid] = b1[tid];
  __syncthreads();

  // A2: degree count
  const unsigned int* eg = wsE + (size_t)g * EPG;
  for (int k = tid; k < EPG; k += NTV) atomicAdd(&s.u.a.cnt[eg[k] & 0xFF], 1);
  __syncthreads();

  // A3 (merged, from v12): scan over padded counts + dinv + cursors + pad-fill
  if (tid < 64) {
    int j = tid;
    int n0 = 2 * j, n1 = 2 * j + 1;
    int r0 = (n0 < NPG) ? s.u.a.cnt[n0] : 0;
    int r1 = (n1 < NPG) ? s.u.a.cnt[n1] : 0;
    int q0 = (r0 + 3) & ~3, q1 = (r1 + 3) & ~3;
    int t = q0 + q1;
    int run = t;
    #pragma unroll
    for (int off = 1; off < 64; off <<= 1) {
      int u = __shfl_up(run, off);
      if (j >= off) run += u;
    }
    int excl = run - t;
    if (n0 < NPG) {
      s.u.a.ptr[n0] = excl;
      s.u.a.dinv[n0] = rsqrtf((float)r0 + 1.0f);
      s.u.a.cnt[n0] = excl;
      for (int k = excl + r0; k < excl + q0; ++k) s.u.a.csr16[k] = (unsigned short)ZROW;
    }
    if (n1 < NPG) {
      int e1 = excl + q0;
      s.u.a.ptr[n1] = e1;
      s.u.a.dinv[n1] = rsqrtf((float)r1 + 1.0f);
      s.u.a.cnt[n1] = e1;
      for (int k = e1 + r1; k < e1 + q1; ++k) s.u.a.csr16[k] = (unsigned short)ZROW;
    }
    if (j == 63) s.u.a.ptr[NPG] = run;
  }
  __syncthreads();

  // A4: CSR fill (offsets pre-multiplied by XSTR)
  for (int k = tid; k < EPG; k += NTV) {
    unsigned int p = eg[k];
    int pos = atomicAdd(&s.u.a.cnt[p & 0xFF], 1);
    s.u.a.csr16[pos] = (unsigned short)(((p >> 8) & 0xFF) * XSTR);
  }
  __syncthreads();

  const float4* xr = reinterpret_cast<const float4*>(x + (size_t)g * NPG * NF);

  // A5: three 32-wide GCN layers
  for (int l = 0; l < 3; ++l) {
    // GEMM, 4-node register-blocked on 200 threads
    if (tid < 25 * 8) {
      int nd = tid >> 3, cq = tid & 7;
      float4 ac0 = make_float4(0,0,0,0), ac1 = ac0, ac2 = ac0, ac3 = ac0;
      #pragma unroll
      for (int kq = 0; kq < 8; ++kq) {
        float4 a0, a1, a2, a3;
        if (l == 0) {
          a0 = xr[(nd     ) * 8 + kq]; a1 = xr[(nd + 25) * 8 + kq];
          a2 = xr[(nd + 50) * 8 + kq]; a3 = xr[(nd + 75) * 8 + kq];
        } else {
          int cb = (l - 1) * NF + kq * 4;
          a0 = ld4(&s.feat[(nd     ) * FSTR + cb]);
          a1 = ld4(&s.feat[(nd + 25) * FSTR + cb]);
          a2 = ld4(&s.feat[(nd + 50) * FSTR + cb]);
          a3 = ld4(&s.feat[(nd + 75) * FSTR + cb]);
        }
        const float v0[4] = {a0.x, a0.y, a0.z, a0.w};
        const float v1[4] = {a1.x, a1.y, a1.z, a1.w};
        const float v2[4] = {a2.x, a2.y, a2.z, a2.w};
        const float v3[4] = {a3.x, a3.y, a3.z, a3.w};
        #pragma unroll
        for (int j = 0; j < 4; ++j) {
          float4 w4 = ld4(&s.u.a.W[(kq * 4 + j) * NF + cq * 4]);
          ac0.x += v0[j]*w4.x; ac0.y += v0[j]*w4.y; ac0.z += v0[j]*w4.z; ac0.w += v0[j]*w4.w;
          ac1.x += v1[j]*w4.x; ac1.y += v1[j]*w4.y; ac1.z += v1[j]*w4.z; ac1.w += v1[j]*w4.w;
          ac2.x += v2[j]*w4.x; ac2.y += v2[j]*w4.y; ac2.z += v2[j]*w4.z; ac2.w += v2[j]*w4.w;
          ac3.x += v3[j]*w4.x; ac3.y += v3[j]*w4.y; ac3.z += v3[j]*w4.z; ac3.w += v3[j]*w4.w;
        }
      }
      float d0 = s.u.a.dinv[nd], d1 = s.u.a.dinv[nd + 25];
      float d2 = s.u.a.dinv[nd + 50], d3 = s.u.a.dinv[nd + 75];
      ac0.x*=d0; ac0.y*=d0; ac0.z*=d0; ac0.w*=d0;
      ac1.x*=d1; ac1.y*=d1; ac1.z*=d1; ac1.w*=d1;
      ac2.x*=d2; ac2.y*=d2; ac2.z*=d2; ac2.w*=d2;
      ac3.x*=d3; ac3.y*=d3; ac3.z*=d3; ac3.w*=d3;
      st4(&s.u.a.hs[(nd     ) * XSTR + cq * 4], ac0);
      st4(&s.u.a.hs[(nd + 25) * XSTR + cq * 4], ac1);
      st4(&s.u.a.hs[(nd + 50) * XSTR + cq * 4], ac2);
      st4(&s.u.a.hs[(nd + 75) * XSTR + cq * 4], ac3);
    }
    __syncthreads();

    // prefetch next weights (AGG never reads W)
    if (l == 0) {
      for (int i = tid; i < NF * NF; i += NTV) s.u.a.W[i] = W2[i];
      if (tid < NF) s.u.a.bias2[1][tid] = b2[tid];
    } else if (l == 1) {
      for (int i = tid; i < NF * NF; i += NTV) s.u.a.W[i] = W3[i];
      if (tid < NF) s.u.a.bias2[0][tid] = b3[tid];
    } else {
      if (tid < NF) s.u.a.W[tid] = W4[tid];
      if (tid == NTV - 1) s.u.a.bias2[1][0] = b4[0];
    }

    // AGG split-gather: item = (d, fq, half); shfl-combine lane^8
    for (int o = tid; o < NPG * 16; o += NTV) {
      int d = o >> 4, fq4 = (o & 7) * 4, h = (o >> 3) & 1;
      int p0 = s.u.a.ptr[d], p1 = s.u.a.ptr[d + 1];
      float4 r = (h == 0) ? ld4(&s.u.a.hs[d * XSTR + fq4])
                          : make_float4(0.f, 0.f, 0.f, 0.f);
      for (int idx = p0 + h * 4; idx < p1; idx += 8) {
        uint2 c2 = *reinterpret_cast<const uint2*>(&s.u.a.csr16[idx]);
        int o0 = c2.x & 0xFFFF, o1 = c2.x >> 16;
        int o2 = c2.y & 0xFFFF, o3 = c2.y >> 16;
        float4 h0 = ld4(&s.u.a.hs[o0 + fq4]);
        float4 h1 = ld4(&s.u.a.hs[o1 + fq4]);
        float4 h2 = ld4(&s.u.a.hs[o2 + fq4]);
        float4 h3 = ld4(&s.u.a.hs[o3 + fq4]);
        r.x += (h0.x + h1.x) + (h2.x + h3.x);
        r.y += (h0.y + h1.y) + (h2.y + h3.y);
        r.z += (h0.z + h1.z) + (h2.z + h3.z);
        r.w += (h0.w + h1.w) + (h2.w + h3.w);
      }
      r.x += __shfl_xor(r.x, 8);
      r.y += __shfl_xor(r.y, 8);
      r.z += __shfl_xor(r.z, 8);
      r.w += __shfl_xor(r.w, 8);
      if (h == 0) {
        const float* bc = s.u.a.bias2[l & 1];
        float4 bq = ld4(&bc[fq4]);
        float di = s.u.a.dinv[d];
        float4 oo;
        oo.x = tanh_fast(di * r.x + bq.x);
        oo.y = tanh_fast(di * r.y + bq.y);
        oo.z = tanh_fast(di * r.z + bq.z);
        oo.w = tanh_fast(di * r.w + bq.w);
        st4(&s.feat[d * FSTR + l * NF + fq4], oo);
      }
    }
    __syncthreads();
  }

  // A6: layer 4 (1-wide)
  if (tid < NPG) {
    float a = 0.f;
    #pragma unroll
    for (int kq = 0; kq < 8; ++kq)
      a += dot4(ld4(&s.feat[tid * FSTR + 2 * NF + kq * 4]), ld4(&s.u.a.W[kq * 4]));
    s.u.a.hs[tid * XSTR] = a * s.u.a.dinv[tid];
  }
  __syncthreads();
  for (int o = tid; o < NPG * 8; o += NTV) {
    int d = o >> 3, p = o & 7;
    int p0 = s.u.a.ptr[d], p1 = s.u.a.ptr[d + 1];
    float r = (p == 0) ? s.u.a.hs[d * XSTR] : 0.f;
    for (int idx = p0 + p; idx < p1; idx += 8) r += s.u.a.hs[s.u.a.csr16[idx]];
    r += __shfl_xor(r, 1);
    r += __shfl_xor(r, 2);
    r += __shfl_xor(r, 4);
    if (p == 0)
      s.feat[d * FSTR + 96] = tanh_fast(s.u.a.dinv[d] * r + s.u.a.bias2[1][0]);
  }
  __syncthreads();

  // A7: stable top-30 by col96 desc (exact f32)
  if (tid < NPG * 4) {
    int i = tid >> 2, p = tid & 3;
    float vv = s.feat[i * FSTR + 96];
    int j0 = p * 25, j1 = j0 + 25;
    int rank = 0;
    for (int j = j0; j < j1; ++j) {
      float vj = s.feat[j * FSTR + 96];
      rank += (vj > vv) || (vj == vv && j < i);
    }
    rank += __shfl_xor(rank, 1);
    rank += __shfl_xor(rank, 2);
    if (p == 0 && rank < KP) s.order[rank] = i;
  }
  __syncthreads();   // phase-A union dead after this

  // B1: pack pooled rows into bf16 A-fragments (one 16B frag per thread)
  {
    int mt = tid >> 8, ks = (tid >> 6) & 3, ln = tid & 63;
    int i = mt * 16 + (ln & 15);
    int k0 = ks * 32 + ((ln >> 4) << 3);
    uint4 pk = make_uint4(0, 0, 0, 0);
    if (i < KP) {
      int row = s.order[i] * FSTR;
      float f[8];
      if (ks < 3) {                       // k0+7 <= 95 < 97 always
        float4 x0 = ld4(&s.feat[row + k0]);
        float4 x1 = ld4(&s.feat[row + k0 + 4]);
        f[0]=x0.x; f[1]=x0.y; f[2]=x0.z; f[3]=x0.w;
        f[4]=x1.x; f[5]=x1.y; f[6]=x1.z; f[7]=x1.w;
      } else {                            // kstep 3: only k=96 is real
        #pragma unroll
        for (int j = 0; j < 8; ++j) f[j] = 0.f;
        if (k0 == 96) f[0] = s.feat[row + 96];
      }
      pk.x = f2bf(f[0]) | (f2bf(f[1]) << 16);
      pk.y = f2bf(f[2]) | (f2bf(f[3]) << 16);
      pk.z = f2bf(f[4]) | (f2bf(f[5]) << 16);
      pk.w = f2bf(f[6]) | (f2bf(f[7]) << 16);
    }
    s.u.b.pooledB[(mt * 4 + ks) * 64 + ln] = pk;
  }
  __syncthreads();

  // B2: priors via MFMA — waves 0..4, each: 2 mtiles x 2 ntiles x 4 ksteps
  if (tid < 5 * 64) {
    int w = tid >> 6, ln = tid & 63;
    #pragma unroll
    for (int mt = 0; mt < 2; ++mt) {
      bf16x8 afr[4];
      #pragma unroll
      for (int ks = 0; ks < 4; ++ks) {
        uint4 raw = s.u.b.pooledB[(mt * 4 + ks) * 64 + ln];
        afr[ks] = __builtin_bit_cast(bf16x8, raw);
      }
      #pragma unroll
      for (int nn = 0; nn < 2; ++nn) {
        int n = w * 2 + nn;
        f32x4 acc = {0.f, 0.f, 0.f, 0.f};
        #pragma unroll
        for (int ks = 0; ks < 4; ++ks) {
          uint4 braw = wcapB[(ks * 10 + n) * 64 + ln];
          bf16x8 bfr = __builtin_bit_cast(bf16x8, braw);
          acc = __builtin_amdgcn_mfma_f32_16x16x32_bf16(afr[ks], bfr, acc, 0, 0, 0);
        }
        int ibase = mt * 16 + ((ln >> 4) << 2);
        int e = ln & 15;
        #pragma unroll
        for (int j = 0; j < 4; ++j) {
          int i = ibase + j;
          if (i < KP) s.u.b.priors[PIDX(i, n) + e] = acc[j];
        }
      }
    }
  }
  __syncthreads();

  // B3: pr_sq + out init
  if (tid < KP * NC) {
    int i = tid / NC, c = tid % NC;
    const float* pr = &s.u.b.priors[PIDX(i, c)];
    float a = 0.f;
    #pragma unroll
    for (int eq = 0; eq < 4; ++eq) { float4 p = ld4(pr + eq * 4); a += dot4(p, p); }
    s.u.b.prsq[tid] = a;
  }
  if (tid < NC * OUTL) {
    int c = tid >> 4, e = tid & 15;
    float a = 0.f;
    #pragma unroll
    for (int i = 0; i < KP; ++i) a += s.u.b.priors[PIDX(i, c) + e];
    s.u.b.outv[tid] = a * (1.0f / KP);
  }
  __syncthreads();

  // B4: routing, 2 barriers/iter (softmax merged into update)
  for (int it = 0; it < NITER; ++it) {
    if (tid < KP * NC) {
      int i = tid / NC, c = tid % NC;
      const float* pr = &s.u.b.priors[PIDX(i, c)];
      const float* ov = &s.u.b.outv[c * OUTL];
      float xy = 0.f, oq = 0.f;
      #pragma unroll
      for (int eq = 0; eq < 4; ++eq) {
        float4 p = ld4(pr + eq * 4);
        float4 o = ld4(ov + eq * 4);
        xy += dot4(p, o); oq += dot4(o, o);
      }
      s.u.b.simbuf[tid] = xy / (s.u.b.prsq[tid] + oq - xy);
    }
    __syncthreads();
    if (tid < NC * OUTL) {
      int c = tid >> 4, e = tid & 15;
      float m = -1e30f;
      #pragma unroll
      for (int i = 0; i < KP; ++i) m = fmaxf(m, s.u.b.simbuf[i * NC + c]);
      float ss = 0.f, a = 0.f;
      #pragma unroll
      for (int i = 0; i < KP; ++i) {
        float w = __expf(s.u.b.simbuf[i * NC + c] - m);
        ss += w;
        a += w * s.u.b.priors[PIDX(i, c) + e];
      }
      s.u.b.outv[tid] = a / ss;
    }
    __syncthreads();
  }

  // B5: classes = ||out||
  if (tid < NC) {
    const float* ov = &s.u.b.outv[tid * OUTL];
    float a = 0.f;
    #pragma unroll
    for (int eq = 0; eq < 4; ++eq) { float4 o = ld4(ov + eq * 4); a += dot4(o, o); }
    out[(size_t)g * NC + tid] = sqrtf(a);
  }
}

// ==================== fused fallback (proven R4 kernel, no ws needed) ====================
struct SMemF {
  float feat[NPG * FSTR];
  union {
    unsigned short epack[EPG];
    float priors[KP * PSTR];
  } u;
  union {
    float hs[NPG * HSTR];
    struct {
      float prsq[KP * NC];
      float simbuf[KP * NC];
      float outv[NC * OUTL];
      float smax[NC];
      float ssum[NC];
      int   order[KP];
    } r;
  } v;
  float W[NF * NF];
  float bias2[2][NF];
  unsigned char csr[EPG];
  int ptr[NPG + 1];
  int cnt[NPG];
  float dinv[NPG];
};

__global__ __launch_bounds__(NTF, 8) void gcn_caps_fused(
    const float* __restrict__ x,
    const int* __restrict__ esrc, const int* __restrict__ edst,
    const float* __restrict__ W1, const float* __restrict__ b1,
    const float* __restrict__ W2, const float* __restrict__ b2,
    const float* __restrict__ W3, const float* __restrict__ b3,
    const float* __restrict__ W4, const float* __restrict__ b4,
    const float* __restrict__ Wcap,
    float* __restrict__ out)
{
  extern __shared__ char smem_raw[];
  SMemF& s = *reinterpret_cast<SMemF*>(smem_raw);
  const int g = blockIdx.x;
  const int tid = threadIdx.x;

  if (tid < NPG) s.cnt[tid] = 0;
  for (int i = tid; i < NF * NF; i += NTF) s.W[i] = W1[i];
  if (tid < NF) s.bias2[0][tid] = b1[tid];
  __syncthreads();

  for (int k = tid; k < EPG; k += NTF) {
    int si = esrc[g + k * NGRAPH] - g * NPG;
    int di = edst[g + k * NGRAPH] - g * NPG;
    s.u.epack[k] = (unsigned short)((si << 8) | di);
    atomicAdd(&s.cnt[di], 1);
  }
  __syncthreads();

  if (tid < 64) {
    int j = tid;
    int a0 = (2 * j < NPG) ? s.cnt[2 * j] : 0;
    int a1 = (2 * j + 1 < NPG) ? s.cnt[2 * j + 1] : 0;
    int t = a0 + a1;
    int run = t;
    #pragma unroll
    for (int off = 1; off < 64; off <<= 1) {
      int u = __shfl_up(run, off);
      if (j >= off) run += u;
    }
    int excl = run - t;
    if (2 * j < NPG) s.ptr[2 * j] = excl;
    if (2 * j + 1 < NPG) s.ptr[2 * j + 1] = excl + a0;
    if (j == 63) s.ptr[NPG] = run;
  }
  __syncthreads();
  if (tid < NPG) {
    s.dinv[tid] = rsqrtf((float)s.cnt[tid] + 1.0f);
    s.cnt[tid] = s.ptr[tid];
  }
  __syncthreads();

  for (int k = tid; k < EPG; k += NTF) {
    int pk = s.u.epack[k];
    int pos = atomicAdd(&s.cnt[pk & 0xFF], 1);
    s.csr[pos] = (unsigned char)(pk >> 8);
  }
  __syncthreads();

  const float4* xr = reinterpret_cast<const float4*>(x + (size_t)g * NPG * NF);
  for (int l = 0; l < 3; ++l) {
    if (tid < NPG * 8) {
      int node = tid >> 3, cq = tid & 7;
      float4 acc = make_float4(0.f, 0.f, 0.f, 0.f);
      #pragma unroll
      for (int kq = 0; kq < 8; ++kq) {
        float4 a4 = (l == 0) ? xr[node * 8 + kq]
                             : ld4(&s.feat[node * FSTR + (l - 1) * NF + kq * 4]);
        const float av[4] = {a4.x, a4.y, a4.z, a4.w};
        #pragma unroll
        for (int j = 0; j < 4; ++j) {
          float4 w4 = ld4(&s.W[(kq * 4 + j) * NF + cq * 4]);
          acc.x += av[j] * w4.x; acc.y += av[j] * w4.y;
          acc.z += av[j] * w4.z; acc.w += av[j] * w4.w;
        }
      }
      float di = s.dinv[node];
      acc.x *= di; acc.y *= di; acc.z *= di; acc.w *= di;
      st4(&s.v.hs[node * HSTR + ((cq ^ (node >> 3)) & 7) * 4], acc);
    }
    __syncthreads();

    if (l == 0) {
      for (int i = tid; i < NF * NF; i += NTF) s.W[i] = W2[i];
      if (tid < NF) s.bias2[1][tid] = b2[tid];
    } else if (l == 1) {
      for (int i = tid; i < NF * NF; i += NTF) s.W[i] = W3[i];
      if (tid < NF) s.bias2[0][tid] = b3[tid];
    } else {
      if (tid < NF) s.W[tid] = W4[tid];
      if (tid == NTF - 1) s.bias2[1][0] = b4[0];
    }

    if (tid < NPG * 8) {
      int d = tid >> 3, fq = tid & 7;
      const float* bc = s.bias2[l & 1];
      float4 b4q = ld4(&bc[fq * 4]);
      float4 r = ld4(&s.v.hs[d * HSTR + ((fq ^ (d >> 3)) & 7) * 4]);
      int p0 = s.ptr[d], p1 = s.ptr[d + 1];
      int idx = p0;
      for (; idx + 1 < p1; idx += 2) {
        int sc0 = s.csr[idx], sc1 = s.csr[idx + 1];
        float4 h0 = ld4(&s.v.hs[sc0 * HSTR + ((fq ^ (sc0 >> 3)) & 7) * 4]);
        float4 h1 = ld4(&s.v.hs[sc1 * HSTR + ((fq ^ (sc1 >> 3)) & 7) * 4]);
        r.x += h0.x + h1.x; r.y += h0.y + h1.y;
        r.z += h0.z + h1.z; r.w += h0.w + h1.w;
      }
      if (idx < p1) {
        int sc = s.csr[idx];
        float4 hq = ld4(&s.v.hs[sc * HSTR + ((fq ^ (sc >> 3)) & 7) * 4]);
        r.x += hq.x; r.y += hq.y; r.z += hq.z; r.w += hq.w;
      }
      float di = s.dinv[d];
      float4 o;
      o.x = tanh_fast(di * r.x + b4q.x);
      o.y = tanh_fast(di * r.y + b4q.y);
      o.z = tanh_fast(di * r.z + b4q.z);
      o.w = tanh_fast(di * r.w + b4q.w);
      st4(&s.feat[d * FSTR + l * NF + fq * 4], o);
    }
    __syncthreads();
  }

  float* hsf = s.v.hs;
  if (tid < NPG) {
    float a = 0.f;
    #pragma unroll
    for (int kq = 0; kq < 8; ++kq)
      a += dot4(ld4(&s.feat[tid * FSTR + 64 + kq * 4]), ld4(&s.W[kq * 4]));
    hsf[tid] = a * s.dinv[tid];
  }
  __syncthreads();
  if (tid < NPG) {
    float r = hsf[tid];
    int p0 = s.ptr[tid], p1 = s.ptr[tid + 1];
    for (int idx = p0; idx < p1; ++idx) r += hsf[s.csr[idx]];
    s.feat[tid * FSTR + 96] = tanh_fast(s.dinv[tid] * r + s.bias2[1][0]);
  }
  __syncthreads();

  if (tid < NPG * 8) {
    int i = tid >> 3, p = tid & 7;
    float vv = s.feat[i * FSTR + 96];
    int j0 = p * 13, j1 = min(NPG, j0 + 13);
    int rank = 0;
    for (int j = j0; j < j1; ++j) {
      float vj = s.feat[j * FSTR + 96];
      rank += (vj > vv) || (vj == vv && j < i);
    }
    rank += __shfl_xor(rank, 1);
    rank += __shfl_xor(rank, 2);
    rank += __shfl_xor(rank, 4);
    if (p == 0 && rank < KP) s.v.r.order[rank] = i;
  }
  __syncthreads();

  if (tid < KP * OUTL) {
    int i = tid >> 4, e = tid & 15;
    int row = s.v.r.order[i] * FSTR;
    float acc[NC];
    #pragma unroll
    for (int c = 0; c < NC; ++c) acc[c] = 0.f;
    for (int c = 0; c < NC; ++c) {
      float a = 0.f;
      for (int l = 0; l < INL; ++l) a += s.feat[row + l] * Wcap[(c * OUTL + e) * INL + l];
      acc[c] = a;
    }
    #pragma unroll
    for (int c = 0; c < NC; ++c) s.u.priors[PIDX(i, c) + e] = acc[c];
  }
  __syncthreads();

  if (tid < KP * NC) {
    int i = tid / NC, c = tid % NC;
    const float* pr = &s.u.priors[PIDX(i, c)];
    float a = 0.f;
    #pragma unroll
    for (int eq = 0; eq < 4; ++eq) { float4 p = ld4(pr + eq * 4); a += dot4(p, p); }
    s.v.r.prsq[tid] = a;
  }
  if (tid < NC * OUTL) {
    int c = tid >> 4, e = tid & 15;
    float a = 0.f;
    #pragma unroll
    for (int i = 0; i < KP; ++i) a += s.u.priors[PIDX(i, c) + e];
    s.v.r.outv[tid] = a * (1.0f / KP);
  }
  __syncthreads();

  for (int it = 0; it < NITER; ++it) {
    if (tid < KP * NC) {
      int i = tid / NC, c = tid % NC;
      const float* pr = &s.u.priors[PIDX(i, c)];
      const float* ov = &s.v.r.outv[c * OUTL];
      float xy = 0.f, oq = 0.f;
      #pragma unroll
      for (int eq = 0; eq < 4; ++eq) {
        float4 p = ld4(pr + eq * 4);
        float4 o = ld4(ov + eq * 4);
        xy += dot4(p, o); oq += dot4(o, o);
      }
      s.v.r.simbuf[tid] = xy / (s.v.r.prsq[tid] + oq - xy);
    }
    __syncthreads();
    if (tid < NC) {
      float m = -1e30f;
      #pragma unroll
      for (int i = 0; i < KP; ++i) m = fmaxf(m, s.v.r.simbuf[i * NC + tid]);
      float ss = 0.f;
      #pragma unroll
      for (int i = 0; i < KP; ++i) ss += __expf(s.v.r.simbuf[i * NC + tid] - m);
      s.v.r.smax[tid] = m;
      s.v.r.ssum[tid] = 1.f / ss;
    }
    __syncthreads();
    if (tid < NC * OUTL) {
      int c = tid >> 4, e = tid & 15;
      float m = s.v.r.smax[c], is = s.v.r.ssum[c], a = 0.f;
      #pragma unroll
      for (int i = 0; i < KP; ++i)
        a += __expf(s.v.r.simbuf[i * NC + c] - m) * s.u.priors[PIDX(i, c) + e];
      s.v.r.outv[tid] = a * is;
    }
    __syncthreads();
  }

  if (tid < NC) {
    const float* ov = &s.v.r.outv[tid * OUTL];
    float a = 0.f;
    #pragma unroll
    for (int eq = 0; eq < 4; ++eq) { float4 o = ld4(ov + eq * 4); a += dot4(o, o); }
    out[(size_t)g * NC + tid] = sqrtf(a);
  }
}

extern "C" void kernel_launch(void* const* d_in, const int* in_sizes, int n_in,
                              void* d_out, int out_size, void* d_ws, size_t ws_size,
                              hipStream_t stream) {
  const float* x    = (const float*)d_in[0];
  const int*   esrc = (const int*)d_in[1];
  const int*   edst = (const int*)d_in[2];
  const float* W1 = (const float*)d_in[4];
  const float* b1 = (const float*)d_in[5];
  const float* W2 = (const float*)d_in[6];
  const float* b2 = (const float*)d_in[7];
  const float* W3 = (const float*)d_in[8];
  const float* b3 = (const float*)d_in[9];
  const float* W4 = (const float*)d_in[10];
  const float* b4 = (const float*)d_in[11];
  const float* Wcap = (const float*)d_in[12];
  float* outp = (float*)d_out;

  if (ws_size >= WS_V10_BYTES) {
    unsigned int* wsE = (unsigned int*)d_ws;
    uint4* wcapB = (uint4*)((char*)d_ws + WS_EDGES_BYTES);
    (void)hipFuncSetAttribute((const void*)gcn_caps_v13,
                              hipFuncAttributeMaxDynamicSharedMemorySize, (int)sizeof(SMemV13));
    prek_edges<<<(EPG / 64) * 16, 256, 0, stream>>>(esrc, edst, wsE);
    prek_capB<<<(WCAPB_UINT4 + 255) / 256, 256, 0, stream>>>(Wcap, wcapB);
    gcn_caps_v13<<<NGRAPH, NTV, sizeof(SMemV13), stream>>>(
        x, wsE, W1, b1, W2, b2, W3, b3, W4, b4, wcapB, outp);
  } else {
    (void)hipFuncSetAttribute((const void*)gcn_caps_fused,
                              hipFuncAttributeMaxDynamicSharedMemorySize, (int)sizeof(SMemF));
    gcn_caps_fused<<<NGRAPH, NTF, sizeof(SMemF), stream>>>(
        x, esrc, edst, W1, b1, W2, b2, W3, b3, W4, b4, Wcap, outp);
  }
}